// Round 1
// baseline (18238.403 us; speedup 1.0000x reference)
//
#include <hip/hip_runtime.h>

// ---------- types ----------
typedef __attribute__((ext_vector_type(8))) short bf16x8;   // 8 bf16 (4 VGPRs)
typedef __attribute__((ext_vector_type(4))) float f32x4;
typedef unsigned short u16;

#define T_SEQ 512
#define HID   1024
#define BATCH 128

__device__ __forceinline__ u16 f2bf(float f) {
  unsigned int u = __float_as_uint(f);
  u += 0x7fffu + ((u >> 16) & 1u);           // RNE
  return (u16)(u >> 16);
}
__device__ __forceinline__ float sigm_(float x) { return 1.f / (1.f + __expf(-x)); }
__device__ __forceinline__ float tanh_(float x) { return 1.f - 2.f / (__expf(2.f * x) + 1.f); }

// ---------- prologue kernels ----------

// z[b][i] = fc_b[i] + sum_o x[b][o] * fc_w[i][o]   (x:[128,256], fc_w:[1024,256])
__global__ void fc_kernel(const float* __restrict__ x, const float* __restrict__ w,
                          const float* __restrict__ bias, float* __restrict__ z) {
  int idx = blockIdx.x * 256 + threadIdx.x;    // 131072 = 128*1024
  int b = idx >> 10, i = idx & 1023;
  const float* xr = x + b * 256;
  const float* wr = w + i * 256;
  float acc = bias[i];
  #pragma unroll 4
  for (int o = 0; o < 256; ++o) acc += xr[o] * wr[o];
  z[idx] = acc;
}

// gx0[b][j] = bih0[j] + bhh0[j] + sum_k z[b][k] * Wih0[j][k]
__global__ void gx0_kernel(const float* __restrict__ z, const float* __restrict__ Wih0,
                           const float* __restrict__ bih, const float* __restrict__ bhh,
                           float* __restrict__ gx0) {
  int idx = blockIdx.x * 256 + threadIdx.x;    // 524288 = 128*4096
  int b = idx >> 12, j = idx & 4095;
  const float* zr = z + b * 1024;              // uniform across block
  const float* wr = Wih0 + (size_t)j * 1024;
  float acc = bih[j] + bhh[j];
  #pragma unroll 4
  for (int k = 0; k < 1024; ++k) acc += zr[k] * wr[k];
  gx0[idx] = acc;
}

__global__ void cvt_bf16(const float* __restrict__ s, u16* __restrict__ d, int n) {
  for (int i = blockIdx.x * blockDim.x + threadIdx.x; i < n; i += gridDim.x * blockDim.x)
    d[i] = f2bf(s[i]);
}

// W1cat[j][0:1024]=Wih1[j][:], [1024:2048]=Whh1[j][:]  (bf16)
__global__ void build_w1cat(const float* __restrict__ wih1, const float* __restrict__ whh1,
                            u16* __restrict__ d) {
  const int n = 4096 * 2048;
  for (int i = blockIdx.x * blockDim.x + threadIdx.x; i < n; i += gridDim.x * blockDim.x) {
    int j = i >> 11, k = i & 2047;
    float v = (k < 1024) ? wih1[((size_t)j << 10) + k] : whh1[((size_t)j << 10) + k - 1024];
    d[i] = f2bf(v);
  }
}

// b1rep[b][j] = bih1[j] + bhh1[j]
__global__ void bias1_rep(const float* __restrict__ bih, const float* __restrict__ bhh,
                          float* __restrict__ d) {
  const int n = 128 * 4096;
  for (int i = blockIdx.x * blockDim.x + threadIdx.x; i < n; i += gridDim.x * blockDim.x)
    d[i] = bih[i & 4095] + bhh[i & 4095];
}

// ---------- fused LSTM step ----------
// gates[b][j] = base[b][j] + sum_seg sum_k A_seg[b][k] * W[j][seg*1024+k]
// then pointwise (i,f,g,o), c update, h out (bf16), optional fp32 h2 out.
// grid 512 = 8 batch-tiles(16) x 64 col-tiles(16); block 256 = 4 waves (one gate each).
template <int NSEG, bool WRITE_F32>
__global__ __launch_bounds__(256, 2)
void lstm_step(const u16* __restrict__ A0, const u16* __restrict__ A1,
               const u16* __restrict__ W, const float* __restrict__ base,
               float* __restrict__ c_buf, u16* __restrict__ h_out,
               float* __restrict__ out_f32) {
  __shared__ u16 Abuf[16][1032];       // +8 shorts pad: row stride 2064B -> 2-way-max LDS conflicts
  __shared__ float gl[4][16][17];

  const int tid = threadIdx.x;
  const int bt = blockIdx.x >> 6;      // batch tile 0..7
  const int ct = blockIdx.x & 63;      // col tile 0..63
  const int lane = tid & 63;
  const int wid = tid >> 6;            // gate 0..3 (i,f,g,o)
  const int l15 = lane & 15;
  const int q = lane >> 4;             // quad 0..3
  const int ldw = NSEG << 10;

  f32x4 acc = {0.f, 0.f, 0.f, 0.f};
  const u16* Wbase = W + (size_t)(wid * 1024 + ct * 16 + l15) * ldw + q * 8;

  for (int seg = 0; seg < NSEG; ++seg) {
    if (seg) __syncthreads();          // Abuf reuse: wait for previous seg's mfma reads
    const u16* As = (seg == 0) ? A0 : A1;
    #pragma unroll
    for (int i = 0; i < 8; ++i) {      // stage 16 rows x 1024 bf16 (32KB), 16B per thread per iter
      int t = tid + i * 256;           // 0..2047
      int r = t >> 7;
      int kc = (t & 127) << 3;
      bf16x8 v = *(const bf16x8*)(As + (((size_t)(bt * 16 + r)) << 10) + kc);
      *(bf16x8*)(&Abuf[r][kc]) = v;
    }
    __syncthreads();

    const u16* Ap = &Abuf[l15][q * 8];         // A[m=lane&15][k=quad*8+j]
    const u16* Wq = Wbase + (seg << 10);       // B[k=quad*8+j][n=lane&15] = W[row n][k]
    #pragma unroll
    for (int kk = 0; kk < 32; ++kk) {
      bf16x8 a = *(const bf16x8*)(Ap + kk * 32);
      bf16x8 b = *(const bf16x8*)(Wq + kk * 32);
      acc = __builtin_amdgcn_mfma_f32_16x16x32_bf16(a, b, acc, 0, 0, 0);
    }
  }

  // D: row=(lane>>4)*4+reg (batch-in-tile), col=lane&15 (h-col-in-tile)
  #pragma unroll
  for (int r = 0; r < 4; ++r) gl[wid][q * 4 + r][l15] = acc[r];
  __syncthreads();

  const int b_loc = tid >> 4, c_loc = tid & 15;         // 256 threads <-> 16x16 tile
  const int b = bt * 16 + b_loc;
  const int col = ct * 16 + c_loc;
  const float* bp = base + ((size_t)b << 12) + col;
  float xi = gl[0][b_loc][c_loc] + bp[0];
  float xf = gl[1][b_loc][c_loc] + bp[1024];
  float xg = gl[2][b_loc][c_loc] + bp[2048];
  float xo = gl[3][b_loc][c_loc] + bp[3072];
  float i_ = sigm_(xi), f_ = sigm_(xf), g_ = tanh_(xg), o_ = sigm_(xo);
  const int ci = (b << 10) + col;
  float c_new = f_ * c_buf[ci] + i_ * g_;
  float h = o_ * tanh_(c_new);
  c_buf[ci] = c_new;
  h_out[ci] = f2bf(h);
  if constexpr (WRITE_F32) out_f32[((size_t)b << 19) + col] = h;   // b*T*H + col
}

// ---------- launch ----------
extern "C" void kernel_launch(void* const* d_in, const int* in_sizes, int n_in,
                              void* d_out, int out_size, void* d_ws, size_t ws_size,
                              hipStream_t stream) {
  (void)in_sizes; (void)n_in; (void)out_size; (void)ws_size;
  const float* x    = (const float*)d_in[0];
  const float* fc_w = (const float*)d_in[1];
  const float* fc_b = (const float*)d_in[2];
  const float* Wih0 = (const float*)d_in[3];
  const float* Whh0 = (const float*)d_in[4];
  const float* bih0 = (const float*)d_in[5];
  const float* bhh0 = (const float*)d_in[6];
  const float* Wih1 = (const float*)d_in[7];
  const float* Whh1 = (const float*)d_in[8];
  const float* bih1 = (const float*)d_in[9];
  const float* bhh1 = (const float*)d_in[10];
  float* out = (float*)d_out;

  char* ws = (char*)d_ws;
  size_t off = 0;
  auto alloc = [&](size_t bytes) -> void* {
    void* p = ws + off;
    off += (bytes + 255) & ~(size_t)255;
    return p;
  };
  float* z      = (float*)alloc((size_t)BATCH * 1024 * 4);
  float* gx0    = (float*)alloc((size_t)BATCH * 4096 * 4);
  u16*   Whh0b  = (u16*)alloc((size_t)4096 * 1024 * 2);
  u16*   W1cat  = (u16*)alloc((size_t)4096 * 2048 * 2);
  float* b1rep  = (float*)alloc((size_t)BATCH * 4096 * 4);
  float* c0     = (float*)alloc((size_t)BATCH * 1024 * 4);
  float* c1     = (float*)alloc((size_t)BATCH * 1024 * 4);
  u16*   h0[2]  = { (u16*)alloc((size_t)BATCH * 1024 * 2), (u16*)alloc((size_t)BATCH * 1024 * 2) };
  u16*   h1[2]  = { (u16*)alloc((size_t)BATCH * 1024 * 2), (u16*)alloc((size_t)BATCH * 1024 * 2) };

  hipMemsetAsync(c0, 0, (size_t)BATCH * 1024 * 4, stream);
  hipMemsetAsync(c1, 0, (size_t)BATCH * 1024 * 4, stream);
  hipMemsetAsync(h0[0], 0, (size_t)BATCH * 1024 * 2, stream);
  hipMemsetAsync(h1[0], 0, (size_t)BATCH * 1024 * 2, stream);

  fc_kernel<<<512, 256, 0, stream>>>(x, fc_w, fc_b, z);
  gx0_kernel<<<2048, 256, 0, stream>>>(z, Wih0, bih0, bhh0, gx0);
  cvt_bf16<<<2048, 256, 0, stream>>>(Whh0, Whh0b, 4096 * 1024);
  build_w1cat<<<2048, 256, 0, stream>>>(Wih1, Whh1, W1cat);
  bias1_rep<<<1024, 256, 0, stream>>>(bih1, bhh1, b1rep);

  for (int t = 0; t < T_SEQ; ++t) {
    int p = t & 1;
    // layer 0: gates = gx0 + h0_prev @ Whh0^T
    lstm_step<1, false><<<512, 256, 0, stream>>>(h0[p], (const u16*)nullptr, Whh0b, gx0,
                                                 c0, h0[1 - p], (float*)nullptr);
    // layer 1: gates = bias1 + h1_t @ Wih1^T + hL1_prev @ Whh1^T  (K concat)
    lstm_step<2, true><<<512, 256, 0, stream>>>(h0[1 - p], h1[p], W1cat, b1rep,
                                                c1, h1[1 - p], out + (size_t)t * 1024);
  }
}

// Round 2
// 12487.148 us; speedup vs baseline: 1.4606x; 1.4606x over previous
//
#include <hip/hip_runtime.h>

typedef __attribute__((ext_vector_type(8))) short bf16x8;   // 8 bf16 (4 VGPRs)
typedef __attribute__((ext_vector_type(4))) float f32x4;
typedef unsigned short u16;

#define T_SEQ 512
#define NBLK  192

__device__ __forceinline__ u16 f2bf(float f) {
  unsigned int u = __float_as_uint(f);
  u += 0x7fffu + ((u >> 16) & 1u);           // RNE
  return (u16)(u >> 16);
}
__device__ __forceinline__ float sigm_(float x) { return 1.f / (1.f + __expf(-x)); }
__device__ __forceinline__ float tanh_(float x) { return 1.f - 2.f / (__expf(2.f * x) + 1.f); }

// ---------- prologue kernels ----------
__global__ void fc_kernel(const float* __restrict__ x, const float* __restrict__ w,
                          const float* __restrict__ bias, float* __restrict__ z) {
  int idx = blockIdx.x * 256 + threadIdx.x;    // 131072 = 128*1024
  int b = idx >> 10, i = idx & 1023;
  const float* xr = x + b * 256;
  const float* wr = w + i * 256;
  float acc = bias[i];
  #pragma unroll 4
  for (int o = 0; o < 256; ++o) acc += xr[o] * wr[o];
  z[idx] = acc;
}

__global__ void gx0_kernel(const float* __restrict__ z, const float* __restrict__ Wih0,
                           const float* __restrict__ bih, const float* __restrict__ bhh,
                           float* __restrict__ gx0) {
  int idx = blockIdx.x * 256 + threadIdx.x;    // 524288 = 128*4096
  int b = idx >> 12, j = idx & 4095;
  const float* zr = z + b * 1024;
  const float* wr = Wih0 + (size_t)j * 1024;
  float acc = bih[j] + bhh[j];
  #pragma unroll 4
  for (int k = 0; k < 1024; ++k) acc += zr[k] * wr[k];
  gx0[idx] = acc;
}

// ---------- persistent fused 2-layer LSTM ----------
// 192 blocks x 512 threads, 1 block/CU (LDS ~147KB). Roles:
//   role0 (bid 0..63):  layer0, W=Whh0 slice, t=p   (gx0 base in regs)
//   role1 (bid 64..127): layer1 input-side, W=Wih1 slice, t=p-1, writes f32 partials
//   role2 (bid 128..191): layer1 recur-side, W=Whh1 slice, t=p-2, adds partials+bias,
//                         pointwise, writes h1 + out
// Each block: 16 h-cols x 4 gates = 64 W rows x K=1024 in LDS (frag-major, conflict-free).
// 8 waves = 4 M-groups(32 batches) x 2 K-halves; K-half reduce through LDS.
__global__ __launch_bounds__(512, 2)
void lstm_persist(const float* __restrict__ Whh0, const float* __restrict__ Wih1,
                  const float* __restrict__ Whh1, const float* __restrict__ gx0,
                  const float* __restrict__ bih1, const float* __restrict__ bhh1,
                  u16* __restrict__ h0ring, u16* __restrict__ h1ring,
                  float* __restrict__ pabuf, float* __restrict__ out,
                  int* __restrict__ bar) {
  // frag-major: wlds[g][k8*16 + n][j], cell = 16B = one B-fragment piece
  __shared__ __align__(16) u16 wlds[4][2048][8];       // 128 KiB
  __shared__ __align__(16) float red[4][64][16];       // 16 KiB

  const int bid = blockIdx.x;
  const int role = bid >> 6;
  const int cslice = bid & 63;
  const int cb = cslice * 16;        // h-col base
  const int tid = threadIdx.x;
  const int w = tid >> 6;            // wave 0..7
  const int lane = tid & 63;
  const int l15 = lane & 15;
  const int q = lane >> 4;
  const int Mg = w & 3;              // M-group: batches Mg*32..+32
  const int kh = w >> 2;             // K-half

  // ---- stage W slice fp32 -> bf16 -> LDS (once) ----
  {
    const float* Wsrc = (role == 0) ? Whh0 : (role == 1) ? Wih1 : Whh1;
    const int r = tid >> 3;          // 0..63: row within slice
    const int g = r >> 4, n = r & 15;
    const int k0 = (tid & 7) * 128;
    const float* src = Wsrc + (((size_t)(g * 1024 + cb + n)) << 10) + k0;
    for (int k = 0; k < 128; k += 4) {
      float4 v = *(const float4*)(src + k);
      ushort4 o;
      o.x = f2bf(v.x); o.y = f2bf(v.y); o.z = f2bf(v.z); o.w = f2bf(v.w);
      const int kk = k0 + k;
      *(ushort4*)&wlds[g][((kk >> 3) << 4) + n][kk & 7] = o;
    }
  }

  // ---- per-thread persistent state ----
  float c_st[2][4];                  // cell state [mt][r] (pointwise waves)
  #pragma unroll
  for (int mt = 0; mt < 2; ++mt)
    #pragma unroll
    for (int r = 0; r < 4; ++r) c_st[mt][r] = 0.f;

  float gx[2][4][4];                 // role0: gx0 base slice
  float b1[4];                       // role2: bias
  if (role == 0 && w < 4) {
    #pragma unroll
    for (int mt = 0; mt < 2; ++mt)
      #pragma unroll
      for (int g = 0; g < 4; ++g)
        #pragma unroll
        for (int r = 0; r < 4; ++r)
          gx[mt][g][r] = gx0[(size_t)(w * 32 + mt * 16 + q * 4 + r) * 4096 + g * 1024 + cb + l15];
  }
  if (role == 2 && w < 4) {
    #pragma unroll
    for (int g = 0; g < 4; ++g)
      b1[g] = bih1[g * 1024 + cb + l15] + bhh1[g * 1024 + cb + l15];
  }
  __syncthreads();

  const size_t HSLOT = (size_t)128 * 1024;   // elems per h ring slot

  for (int p = 0; p < T_SEQ + 2; ++p) {
    const int t = p - role;
    if (t >= 0 && t < T_SEQ) {
      // A operand: role0: h0[t-1]; role1: h0[t]; role2: h1[t-1]
      const u16* A;
      if (role == 1)      A = h0ring + (size_t)(t & 1) * HSLOT;
      else if (role == 0) A = h0ring + (size_t)((t + 1) & 1) * HSLOT;
      else                A = h1ring + (size_t)((t + 1) & 1) * HSLOT;

      const int kbase = kh * 512;
      const u16* Ap = A + (((size_t)(Mg * 32 + l15)) << 10) + kbase + q * 8;
      const int cellbase = ((kbase >> 3) + q) * 16 + l15;   // + kk*64

      f32x4 acc0[4] = {{0.f,0.f,0.f,0.f},{0.f,0.f,0.f,0.f},{0.f,0.f,0.f,0.f},{0.f,0.f,0.f,0.f}};
      f32x4 acc1[4] = {{0.f,0.f,0.f,0.f},{0.f,0.f,0.f,0.f},{0.f,0.f,0.f,0.f},{0.f,0.f,0.f,0.f}};

      #pragma unroll
      for (int kk = 0; kk < 16; ++kk) {
        bf16x8 a0 = *(const bf16x8*)(Ap + kk * 32);
        bf16x8 a1 = *(const bf16x8*)(Ap + (16 << 10) + kk * 32);
        #pragma unroll
        for (int g = 0; g < 4; ++g) {
          bf16x8 b = *(const bf16x8*)&wlds[g][cellbase + kk * 64][0];
          acc0[g] = __builtin_amdgcn_mfma_f32_16x16x32_bf16(a0, b, acc0[g], 0, 0, 0);
          acc1[g] = __builtin_amdgcn_mfma_f32_16x16x32_bf16(a1, b, acc1[g], 0, 0, 0);
        }
      }

      // ---- K-half reduction via LDS (M-tile at a time, 16KB buffer) ----
      if (w >= 4) {
        #pragma unroll
        for (int g = 0; g < 4; ++g) *(f32x4*)&red[w - 4][lane][g * 4] = acc0[g];
      }
      __syncthreads();
      if (w < 4) {
        #pragma unroll
        for (int g = 0; g < 4; ++g) acc0[g] += *(const f32x4*)&red[w][lane][g * 4];
      }
      __syncthreads();
      if (w >= 4) {
        #pragma unroll
        for (int g = 0; g < 4; ++g) *(f32x4*)&red[w - 4][lane][g * 4] = acc1[g];
      }
      __syncthreads();
      if (w < 4) {
        #pragma unroll
        for (int g = 0; g < 4; ++g) acc1[g] += *(const f32x4*)&red[w][lane][g * 4];

        if (role == 1) {
          // store full-K partials, coalesced f32x4
          float* pw = pabuf + (size_t)(t & 1) * 524288 + (size_t)(cslice * 4 + w) * 2048;
          #pragma unroll
          for (int g = 0; g < 4; ++g) {
            *(f32x4*)(pw + (g * 256) + lane * 4)       = acc0[g];
            *(f32x4*)(pw + ((4 + g) * 256) + lane * 4) = acc1[g];
          }
        } else {
          const float* pr = (role == 2)
              ? pabuf + (size_t)(t & 1) * 524288 + (size_t)(cslice * 4 + w) * 2048
              : (const float*)0;
          #pragma unroll
          for (int mt = 0; mt < 2; ++mt) {
            #pragma unroll
            for (int r = 0; r < 4; ++r) {
              float xi, xf, xg, xo;
              f32x4* a = mt ? acc1 : acc0;
              if (role == 0) {
                xi = a[0][r] + gx[mt][0][r];
                xf = a[1][r] + gx[mt][1][r];
                xg = a[2][r] + gx[mt][2][r];
                xo = a[3][r] + gx[mt][3][r];
              } else {
                xi = a[0][r] + pr[(mt * 4 + 0) * 256 + lane * 4 + r] + b1[0];
                xf = a[1][r] + pr[(mt * 4 + 1) * 256 + lane * 4 + r] + b1[1];
                xg = a[2][r] + pr[(mt * 4 + 2) * 256 + lane * 4 + r] + b1[2];
                xo = a[3][r] + pr[(mt * 4 + 3) * 256 + lane * 4 + r] + b1[3];
              }
              float i_ = sigm_(xi), f_ = sigm_(xf), g_ = tanh_(xg), o_ = sigm_(xo);
              float cn = f_ * c_st[mt][r] + i_ * g_;
              c_st[mt][r] = cn;
              float h = o_ * tanh_(cn);
              const int row = w * 32 + mt * 16 + q * 4 + r;    // batch
              const int col = cb + l15;
              if (role == 0) {
                h0ring[(size_t)(t & 1) * HSLOT + ((size_t)row << 10) + col] = f2bf(h);
              } else {
                h1ring[(size_t)(t & 1) * HSLOT + ((size_t)row << 10) + col] = f2bf(h);
                out[(size_t)row * ((size_t)T_SEQ * 1024) + (size_t)t * 1024 + col] = h;
              }
            }
          }
        }
      }
    }

    // ---- grid barrier (all 192 blocks co-resident by construction) ----
    __syncthreads();                       // drains each thread's vmcnt before barrier
    if (tid == 0) {
      __builtin_amdgcn_fence(__ATOMIC_RELEASE, "agent");     // L2 writeback: publish stores
      __hip_atomic_fetch_add(bar, 1, __ATOMIC_RELAXED, __HIP_MEMORY_SCOPE_AGENT);
      const int target = (p + 1) * NBLK;
      while (__hip_atomic_load(bar, __ATOMIC_RELAXED, __HIP_MEMORY_SCOPE_AGENT) < target)
        __builtin_amdgcn_s_sleep(2);
      __builtin_amdgcn_fence(__ATOMIC_ACQUIRE, "agent");     // invalidate L1/L2 stale lines
    }
    __syncthreads();
  }
}

// ---------- launch ----------
extern "C" void kernel_launch(void* const* d_in, const int* in_sizes, int n_in,
                              void* d_out, int out_size, void* d_ws, size_t ws_size,
                              hipStream_t stream) {
  (void)in_sizes; (void)n_in; (void)out_size; (void)ws_size;
  const float* x    = (const float*)d_in[0];
  const float* fc_w = (const float*)d_in[1];
  const float* fc_b = (const float*)d_in[2];
  const float* Wih0 = (const float*)d_in[3];
  const float* Whh0 = (const float*)d_in[4];
  const float* bih0 = (const float*)d_in[5];
  const float* bhh0 = (const float*)d_in[6];
  const float* Wih1 = (const float*)d_in[7];
  const float* Whh1 = (const float*)d_in[8];
  const float* bih1 = (const float*)d_in[9];
  const float* bhh1 = (const float*)d_in[10];
  float* out = (float*)d_out;

  char* ws = (char*)d_ws;
  size_t off = 0;
  auto alloc = [&](size_t bytes) -> void* {
    void* p = ws + off;
    off += (bytes + 255) & ~(size_t)255;
    return p;
  };
  float* z      = (float*)alloc((size_t)128 * 1024 * 4);
  float* gx0    = (float*)alloc((size_t)128 * 4096 * 4);
  u16*   h0ring = (u16*)alloc((size_t)2 * 128 * 1024 * 2);
  u16*   h1ring = (u16*)alloc((size_t)2 * 128 * 1024 * 2);
  float* pabuf  = (float*)alloc((size_t)2 * 524288 * 4);
  int*   bar    = (int*)alloc(256);

  hipMemsetAsync(h0ring, 0, (size_t)2 * 128 * 1024 * 2, stream);
  hipMemsetAsync(h1ring, 0, (size_t)2 * 128 * 1024 * 2, stream);
  hipMemsetAsync(bar, 0, 256, stream);

  fc_kernel<<<512, 256, 0, stream>>>(x, fc_w, fc_b, z);
  gx0_kernel<<<2048, 256, 0, stream>>>(z, Wih0, bih0, bhh0, gx0);

  lstm_persist<<<NBLK, 512, 0, stream>>>(Whh0, Wih1, Whh1, gx0, bih1, bhh1,
                                         h0ring, h1ring, pabuf, out, bar);
}

// Round 3
// 10884.278 us; speedup vs baseline: 1.6757x; 1.1473x over previous
//
#include <hip/hip_runtime.h>

typedef __attribute__((ext_vector_type(8))) short bf16x8;   // 8 bf16 (4 VGPRs)
typedef __attribute__((ext_vector_type(4))) float f32x4;
typedef unsigned short u16;

#define T_SEQ 512
#define NBLK  192

__device__ __forceinline__ u16 f2bf(float f) {
  unsigned int u = __float_as_uint(f);
  u += 0x7fffu + ((u >> 16) & 1u);           // RNE
  return (u16)(u >> 16);
}
__device__ __forceinline__ float sigm_(float x) { return 1.f / (1.f + __expf(-x)); }
__device__ __forceinline__ float tanh_(float x) { return 1.f - 2.f / (__expf(2.f * x) + 1.f); }

// agent-scope (device-coherent) element access: reaches IF$ without L2 dirty
// lines -> no release fence / buffer_wbl2 needed. Compiler tracks vmcnt.
template <typename T>
__device__ __forceinline__ void st_agent(T* p, T v) {
  __hip_atomic_store(p, v, __ATOMIC_RELAXED, __HIP_MEMORY_SCOPE_AGENT);
}
template <typename T>
__device__ __forceinline__ T ld_agent(const T* p) {
  return __hip_atomic_load(p, __ATOMIC_RELAXED, __HIP_MEMORY_SCOPE_AGENT);
}

// ---------- prologue kernels ----------
__global__ void fc_kernel(const float* __restrict__ x, const float* __restrict__ w,
                          const float* __restrict__ bias, float* __restrict__ z) {
  int idx = blockIdx.x * 256 + threadIdx.x;    // 131072 = 128*1024
  int b = idx >> 10, i = idx & 1023;
  const float* xr = x + b * 256;
  const float* wr = w + i * 256;
  float acc = bias[i];
  #pragma unroll 4
  for (int o = 0; o < 256; ++o) acc += xr[o] * wr[o];
  z[idx] = acc;
}

__global__ void gx0_kernel(const float* __restrict__ z, const float* __restrict__ Wih0,
                           const float* __restrict__ bih, const float* __restrict__ bhh,
                           float* __restrict__ gx0) {
  int idx = blockIdx.x * 256 + threadIdx.x;    // 524288 = 128*4096
  int b = idx >> 12, j = idx & 4095;
  const float* zr = z + b * 1024;
  const float* wr = Wih0 + (size_t)j * 1024;
  float acc = bih[j] + bhh[j];
  #pragma unroll 4
  for (int k = 0; k < 1024; ++k) acc += zr[k] * wr[k];
  gx0[idx] = acc;
}

// ---------- persistent fused 2-layer LSTM ----------
// 192 blocks x 512 threads, 1 block/CU (LDS ~147KB). Roles:
//   role0 (bid 0..63):  layer0, W=Whh0 slice, t=p   (gx0 base in regs)
//   role1 (bid 64..127): layer1 input-side, W=Wih1 slice, t=p-1, writes f32 partials
//   role2 (bid 128..191): layer1 recur-side, W=Whh1 slice, t=p-2, adds partials+bias,
//                         pointwise, writes h1 + out
// Cross-block data via agent-scope atomics (IF$-coherent, write-through);
// A-operand reads stay normal cached loads (per-XCD L2 multicast). Barrier
// keeps ONLY the acquire fence (buffer_inv) -- no wbl2 / HBM round trip.
__global__ __launch_bounds__(512, 2)
void lstm_persist(const float* __restrict__ Whh0, const float* __restrict__ Wih1,
                  const float* __restrict__ Whh1, const float* __restrict__ gx0,
                  const float* __restrict__ bih1, const float* __restrict__ bhh1,
                  u16* __restrict__ h0ring, u16* __restrict__ h1ring,
                  float* __restrict__ pabuf, float* __restrict__ out,
                  int* __restrict__ bar) {
  // frag-major: wlds[g][k8*16 + n][j], cell = 16B = one B-fragment piece
  __shared__ __align__(16) u16 wlds[4][2048][8];       // 128 KiB
  __shared__ __align__(16) float red[4][64][16];       // 16 KiB

  const int bid = blockIdx.x;
  const int role = bid >> 6;
  const int cslice = bid & 63;
  const int cb = cslice * 16;        // h-col base
  const int tid = threadIdx.x;
  const int w = tid >> 6;            // wave 0..7
  const int lane = tid & 63;
  const int l15 = lane & 15;
  const int q = lane >> 4;
  const int Mg = w & 3;              // M-group: batches Mg*32..+32
  const int kh = w >> 2;             // K-half

  // ---- stage W slice fp32 -> bf16 -> LDS (once) ----
  {
    const float* Wsrc = (role == 0) ? Whh0 : (role == 1) ? Wih1 : Whh1;
    const int r = tid >> 3;          // 0..63: row within slice
    const int g = r >> 4, n = r & 15;
    const int k0 = (tid & 7) * 128;
    const float* src = Wsrc + (((size_t)(g * 1024 + cb + n)) << 10) + k0;
    for (int k = 0; k < 128; k += 4) {
      float4 v = *(const float4*)(src + k);
      ushort4 o;
      o.x = f2bf(v.x); o.y = f2bf(v.y); o.z = f2bf(v.z); o.w = f2bf(v.w);
      const int kk = k0 + k;
      *(ushort4*)&wlds[g][((kk >> 3) << 4) + n][kk & 7] = o;
    }
  }

  // ---- per-thread persistent state ----
  float c_st[2][4];                  // cell state [mt][r] (pointwise waves)
  #pragma unroll
  for (int mt = 0; mt < 2; ++mt)
    #pragma unroll
    for (int r = 0; r < 4; ++r) c_st[mt][r] = 0.f;

  float gx[2][4][4];                 // role0: gx0 base slice
  float b1[4];                       // role2: bias
  if (role == 0 && w < 4) {
    #pragma unroll
    for (int mt = 0; mt < 2; ++mt)
      #pragma unroll
      for (int g = 0; g < 4; ++g)
        #pragma unroll
        for (int r = 0; r < 4; ++r)
          gx[mt][g][r] = gx0[(size_t)(w * 32 + mt * 16 + q * 4 + r) * 4096 + g * 1024 + cb + l15];
  }
  if (role == 2 && w < 4) {
    #pragma unroll
    for (int g = 0; g < 4; ++g)
      b1[g] = bih1[g * 1024 + cb + l15] + bhh1[g * 1024 + cb + l15];
  }
  __syncthreads();

  const size_t HSLOT = (size_t)128 * 1024;   // elems per h ring slot

  for (int p = 0; p < T_SEQ + 2; ++p) {
    const int t = p - role;
    if (t >= 0 && t < T_SEQ) {
      // A operand: role0: h0[t-1]; role1: h0[t]; role2: h1[t-1]
      const u16* A;
      if (role == 1)      A = h0ring + (size_t)(t & 1) * HSLOT;
      else if (role == 0) A = h0ring + (size_t)((t + 1) & 1) * HSLOT;
      else                A = h1ring + (size_t)((t + 1) & 1) * HSLOT;

      const int kbase = kh * 512;
      const u16* Ap = A + (((size_t)(Mg * 32 + l15)) << 10) + kbase + q * 8;
      const int cellbase = ((kbase >> 3) + q) * 16 + l15;   // + kk*64

      f32x4 acc0[4] = {{0.f,0.f,0.f,0.f},{0.f,0.f,0.f,0.f},{0.f,0.f,0.f,0.f},{0.f,0.f,0.f,0.f}};
      f32x4 acc1[4] = {{0.f,0.f,0.f,0.f},{0.f,0.f,0.f,0.f},{0.f,0.f,0.f,0.f},{0.f,0.f,0.f,0.f}};

      #pragma unroll
      for (int kk = 0; kk < 16; ++kk) {
        bf16x8 a0 = *(const bf16x8*)(Ap + kk * 32);
        bf16x8 a1 = *(const bf16x8*)(Ap + (16 << 10) + kk * 32);
        #pragma unroll
        for (int g = 0; g < 4; ++g) {
          bf16x8 b = *(const bf16x8*)&wlds[g][cellbase + kk * 64][0];
          acc0[g] = __builtin_amdgcn_mfma_f32_16x16x32_bf16(a0, b, acc0[g], 0, 0, 0);
          acc1[g] = __builtin_amdgcn_mfma_f32_16x16x32_bf16(a1, b, acc1[g], 0, 0, 0);
        }
      }

      // ---- K-half reduction via LDS ----
      if (w >= 4) {
        #pragma unroll
        for (int g = 0; g < 4; ++g) *(f32x4*)&red[w - 4][lane][g * 4] = acc0[g];
      }
      __syncthreads();
      if (w < 4) {
        #pragma unroll
        for (int g = 0; g < 4; ++g) acc0[g] += *(const f32x4*)&red[w][lane][g * 4];
      }
      __syncthreads();
      if (w >= 4) {
        #pragma unroll
        for (int g = 0; g < 4; ++g) *(f32x4*)&red[w - 4][lane][g * 4] = acc1[g];
      }
      __syncthreads();
      if (w < 4) {
        #pragma unroll
        for (int g = 0; g < 4; ++g) acc1[g] += *(const f32x4*)&red[w][lane][g * 4];

        if (role == 1) {
          // store full-K partials (agent scope: IF$-coherent)
          float* pw = pabuf + (size_t)(t & 1) * 524288 + (size_t)(cslice * 4 + w) * 2048;
          #pragma unroll
          for (int g = 0; g < 4; ++g) {
            #pragma unroll
            for (int r = 0; r < 4; ++r) {
              st_agent(pw + g * 256 + lane * 4 + r,       acc0[g][r]);
              st_agent(pw + (4 + g) * 256 + lane * 4 + r, acc1[g][r]);
            }
          }
        } else {
          const float* pr = (role == 2)
              ? pabuf + (size_t)(t & 1) * 524288 + (size_t)(cslice * 4 + w) * 2048
              : (const float*)0;
          #pragma unroll
          for (int mt = 0; mt < 2; ++mt) {
            #pragma unroll
            for (int r = 0; r < 4; ++r) {
              float xi, xf, xg, xo;
              f32x4* a = mt ? acc1 : acc0;
              if (role == 0) {
                xi = a[0][r] + gx[mt][0][r];
                xf = a[1][r] + gx[mt][1][r];
                xg = a[2][r] + gx[mt][2][r];
                xo = a[3][r] + gx[mt][3][r];
              } else {
                xi = a[0][r] + ld_agent(pr + (mt * 4 + 0) * 256 + lane * 4 + r) + b1[0];
                xf = a[1][r] + ld_agent(pr + (mt * 4 + 1) * 256 + lane * 4 + r) + b1[1];
                xg = a[2][r] + ld_agent(pr + (mt * 4 + 2) * 256 + lane * 4 + r) + b1[2];
                xo = a[3][r] + ld_agent(pr + (mt * 4 + 3) * 256 + lane * 4 + r) + b1[3];
              }
              float i_ = sigm_(xi), f_ = sigm_(xf), g_ = tanh_(xg), o_ = sigm_(xo);
              float cn = f_ * c_st[mt][r] + i_ * g_;
              c_st[mt][r] = cn;
              float h = o_ * tanh_(cn);
              const int row = w * 32 + mt * 16 + q * 4 + r;    // batch
              const int col = cb + l15;
              if (role == 0) {
                st_agent(h0ring + (size_t)(t & 1) * HSLOT + ((size_t)row << 10) + col, f2bf(h));
              } else {
                st_agent(h1ring + (size_t)(t & 1) * HSLOT + ((size_t)row << 10) + col, f2bf(h));
                st_agent(out + (size_t)row * ((size_t)T_SEQ * 1024) + (size_t)t * 1024 + col, h);
              }
            }
          }
        }
      }
    }

    // ---- grid barrier (all 192 blocks co-resident; 1 block/CU) ----
    // __syncthreads drains every wave's vmcnt -> all agent stores are at the
    // coherence point (IF$) before the arrive. No release fence (no wbl2).
    __syncthreads();
    if (tid == 0) {
      __hip_atomic_fetch_add(bar, 1, __ATOMIC_RELAXED, __HIP_MEMORY_SCOPE_AGENT);
      const int target = (p + 1) * NBLK;
      while (__hip_atomic_load(bar, __ATOMIC_RELAXED, __HIP_MEMORY_SCOPE_AGENT) < target)
        __builtin_amdgcn_s_sleep(2);
      __builtin_amdgcn_fence(__ATOMIC_ACQUIRE, "agent");     // buffer_inv: drop stale L1/L2
    }
    __syncthreads();
  }
}

// ---------- launch ----------
extern "C" void kernel_launch(void* const* d_in, const int* in_sizes, int n_in,
                              void* d_out, int out_size, void* d_ws, size_t ws_size,
                              hipStream_t stream) {
  (void)in_sizes; (void)n_in; (void)out_size; (void)ws_size;
  const float* x    = (const float*)d_in[0];
  const float* fc_w = (const float*)d_in[1];
  const float* fc_b = (const float*)d_in[2];
  const float* Wih0 = (const float*)d_in[3];
  const float* Whh0 = (const float*)d_in[4];
  const float* bih0 = (const float*)d_in[5];
  const float* bhh0 = (const float*)d_in[6];
  const float* Wih1 = (const float*)d_in[7];
  const float* Whh1 = (const float*)d_in[8];
  const float* bih1 = (const float*)d_in[9];
  const float* bhh1 = (const float*)d_in[10];
  float* out = (float*)d_out;

  char* ws = (char*)d_ws;
  size_t off = 0;
  auto alloc = [&](size_t bytes) -> void* {
    void* p = ws + off;
    off += (bytes + 255) & ~(size_t)255;
    return p;
  };
  float* z      = (float*)alloc((size_t)128 * 1024 * 4);
  float* gx0    = (float*)alloc((size_t)128 * 4096 * 4);
  u16*   h0ring = (u16*)alloc((size_t)2 * 128 * 1024 * 2);
  u16*   h1ring = (u16*)alloc((size_t)2 * 128 * 1024 * 2);
  float* pabuf  = (float*)alloc((size_t)2 * 524288 * 4);
  int*   bar    = (int*)alloc(256);

  hipMemsetAsync(h0ring, 0, (size_t)2 * 128 * 1024 * 2, stream);
  hipMemsetAsync(h1ring, 0, (size_t)2 * 128 * 1024 * 2, stream);
  hipMemsetAsync(bar, 0, 256, stream);

  fc_kernel<<<512, 256, 0, stream>>>(x, fc_w, fc_b, z);
  gx0_kernel<<<2048, 256, 0, stream>>>(z, Wih0, bih0, bhh0, gx0);

  lstm_persist<<<NBLK, 512, 0, stream>>>(Whh0, Wih1, Whh1, gx0, bih1, bhh1,
                                         h0ring, h1ring, pabuf, out, bar);
}

// Round 5
// 7755.902 us; speedup vs baseline: 2.3516x; 1.4034x over previous
//
#include <hip/hip_runtime.h>

typedef __attribute__((ext_vector_type(8))) short bf16x8;   // 8 bf16 (4 VGPRs)
typedef __attribute__((ext_vector_type(4))) float f32x4;
typedef unsigned short u16;
typedef unsigned long long u64;

#define T_SEQ 512
#define NBLK  192

__device__ __forceinline__ u16 f2bf(float f) {
  unsigned int u = __float_as_uint(f);
  u += 0x7fffu + ((u >> 16) & 1u);           // RNE
  return (u16)(u >> 16);
}
__device__ __forceinline__ float sigm_(float x) { return 1.f / (1.f + __expf(-x)); }
__device__ __forceinline__ float tanh_(float x) { return 1.f - 2.f / (__expf(2.f * x) + 1.f); }

// agent-scope (device-coherent) access. COMPILER-VISIBLE (unlike inline asm):
// tracked by vmcnt insertion, drained before every s_barrier. No wbl2 needed.
template <typename T>
__device__ __forceinline__ void st_agent(T* p, T v) {
  __hip_atomic_store(p, v, __ATOMIC_RELAXED, __HIP_MEMORY_SCOPE_AGENT);
}
template <typename T>
__device__ __forceinline__ T ld_agent(const T* p) {
  return __hip_atomic_load(p, __ATOMIC_RELAXED, __HIP_MEMORY_SCOPE_AGENT);
}
__device__ __forceinline__ u64 pack2f(float a, float b) {
  return (u64)__float_as_uint(a) | ((u64)__float_as_uint(b) << 32);
}
__device__ __forceinline__ u64 pack4bf(f32x4 v) {
  return (u64)f2bf(v[0]) | ((u64)f2bf(v[1]) << 16) |
         ((u64)f2bf(v[2]) << 32) | ((u64)f2bf(v[3]) << 48);
}

// ---------- prologue kernels ----------
__global__ void fc_kernel(const float* __restrict__ x, const float* __restrict__ w,
                          const float* __restrict__ bias, float* __restrict__ z) {
  int idx = blockIdx.x * 256 + threadIdx.x;    // 131072 = 128*1024
  int b = idx >> 10, i = idx & 1023;
  const float* xr = x + b * 256;
  const float* wr = w + i * 256;
  float acc = bias[i];
  #pragma unroll 4
  for (int o = 0; o < 256; ++o) acc += xr[o] * wr[o];
  z[idx] = acc;
}

__global__ void gx0_kernel(const float* __restrict__ z, const float* __restrict__ Wih0,
                           const float* __restrict__ bih, const float* __restrict__ bhh,
                           float* __restrict__ gx0) {
  int idx = blockIdx.x * 256 + threadIdx.x;    // 524288 = 128*4096
  int b = idx >> 12, j = idx & 4095;
  const float* zr = z + b * 1024;
  const float* wr = Wih0 + (size_t)j * 1024;
  float acc = bih[j] + bhh[j];
  #pragma unroll 4
  for (int k = 0; k < 1024; ++k) acc += zr[k] * wr[k];
  gx0[idx] = acc;
}

// ---------- persistent fused 2-layer LSTM ----------
// 192 blocks x 512 threads, 1 block/CU. Roles:
//   role0: layer0 (W=Whh0 slice, t=p), role1: layer1 input-side -> pabuf (t=p-1),
//   role2: layer1 recur-side + pointwise + out (t=p-2).
// vs R3: flag/epoch barrier (no contended RMW), u64 atomic pabuf,
// LDS-staged coalesced h stores, plain cached out stores. NO inline asm.
__global__ __launch_bounds__(512, 2)
void lstm_persist(const float* __restrict__ Whh0, const float* __restrict__ Wih1,
                  const float* __restrict__ Whh1, const float* __restrict__ gx0,
                  const float* __restrict__ bih1, const float* __restrict__ bhh1,
                  u16* __restrict__ h0ring, u16* __restrict__ h1ring,
                  float* __restrict__ pabuf, float* __restrict__ out,
                  int* __restrict__ flags, int* __restrict__ epoch) {
  __shared__ __align__(16) u16 wlds[4][2048][8];       // 128 KiB (frag-major W)
  __shared__ __align__(16) float red[4][64][16];       // 16 KiB (K-half reduce)
  __shared__ __align__(16) float stage[128][16];       // 8 KiB (h staging)

  const int bid = blockIdx.x;
  const int role = bid >> 6;
  const int cslice = bid & 63;
  const int cb = cslice * 16;        // h-col base
  const int tid = threadIdx.x;
  const int w = tid >> 6;            // wave 0..7
  const int lane = tid & 63;
  const int l15 = lane & 15;
  const int q = lane >> 4;
  const int Mg = w & 3;              // M-group: batches Mg*32..+32
  const int kh = w >> 2;             // K-half

  // ---- stage W slice fp32 -> bf16 -> LDS (once) ----
  {
    const float* Wsrc = (role == 0) ? Whh0 : (role == 1) ? Wih1 : Whh1;
    const int r = tid >> 3;          // 0..63: row within slice
    const int g = r >> 4, n = r & 15;
    const int k0 = (tid & 7) * 128;
    const float* src = Wsrc + (((size_t)(g * 1024 + cb + n)) << 10) + k0;
    for (int k = 0; k < 128; k += 4) {
      float4 v = *(const float4*)(src + k);
      ushort4 o;
      o.x = f2bf(v.x); o.y = f2bf(v.y); o.z = f2bf(v.z); o.w = f2bf(v.w);
      const int kk = k0 + k;
      *(ushort4*)&wlds[g][((kk >> 3) << 4) + n][kk & 7] = o;
    }
  }

  // ---- per-thread persistent state ----
  float c_st[2][4];
  #pragma unroll
  for (int mt = 0; mt < 2; ++mt)
    #pragma unroll
    for (int r = 0; r < 4; ++r) c_st[mt][r] = 0.f;

  float gx[2][4][4];                 // role0: gx0 base slice
  float b1[4];                       // role2: bias
  if (role == 0 && w < 4) {
    #pragma unroll
    for (int mt = 0; mt < 2; ++mt)
      #pragma unroll
      for (int g = 0; g < 4; ++g)
        #pragma unroll
        for (int r = 0; r < 4; ++r)
          gx[mt][g][r] = gx0[(size_t)(w * 32 + mt * 16 + q * 4 + r) * 4096 + g * 1024 + cb + l15];
  }
  if (role == 2 && w < 4) {
    #pragma unroll
    for (int g = 0; g < 4; ++g)
      b1[g] = bih1[g * 1024 + cb + l15] + bhh1[g * 1024 + cb + l15];
  }
  __syncthreads();

  const size_t HSLOT = (size_t)128 * 1024;   // elems per h ring slot

  for (int p = 0; p < T_SEQ + 2; ++p) {
    const int t = p - role;
    if (t >= 0 && t < T_SEQ) {
      const u16* A;
      if (role == 1)      A = h0ring + (size_t)(t & 1) * HSLOT;
      else if (role == 0) A = h0ring + (size_t)((t + 1) & 1) * HSLOT;
      else                A = h1ring + (size_t)((t + 1) & 1) * HSLOT;

      const int kbase = kh * 512;
      const u16* Ap = A + (((size_t)(Mg * 32 + l15)) << 10) + kbase + q * 8;
      const int cellbase = ((kbase >> 3) + q) * 16 + l15;   // + kk*64

      f32x4 acc0[4] = {{0.f,0.f,0.f,0.f},{0.f,0.f,0.f,0.f},{0.f,0.f,0.f,0.f},{0.f,0.f,0.f,0.f}};
      f32x4 acc1[4] = {{0.f,0.f,0.f,0.f},{0.f,0.f,0.f,0.f},{0.f,0.f,0.f,0.f},{0.f,0.f,0.f,0.f}};

      #pragma unroll
      for (int kk = 0; kk < 16; ++kk) {
        bf16x8 a0 = *(const bf16x8*)(Ap + kk * 32);
        bf16x8 a1 = *(const bf16x8*)(Ap + (16 << 10) + kk * 32);
        #pragma unroll
        for (int g = 0; g < 4; ++g) {
          bf16x8 b = *(const bf16x8*)&wlds[g][cellbase + kk * 64][0];
          acc0[g] = __builtin_amdgcn_mfma_f32_16x16x32_bf16(a0, b, acc0[g], 0, 0, 0);
          acc1[g] = __builtin_amdgcn_mfma_f32_16x16x32_bf16(a1, b, acc1[g], 0, 0, 0);
        }
      }

      // role2: issue pabuf loads early (u64 atomics; compiler inserts the wait
      // before first use, the LDS reduction hides the latency)
      u64 pa64[16];
      const float* pr = pabuf + (size_t)(t & 1) * 524288 + (size_t)(cslice * 4 + w) * 2048;
      if (role == 2 && w < 4) {
        #pragma unroll
        for (int j = 0; j < 8; ++j) {
          pa64[j * 2]     = ld_agent((const u64*)pr + j * 128 + lane * 2);
          pa64[j * 2 + 1] = ld_agent((const u64*)pr + j * 128 + lane * 2 + 1);
        }
      }

      // ---- K-half reduction via LDS ----
      if (w >= 4) {
        #pragma unroll
        for (int g = 0; g < 4; ++g) *(f32x4*)&red[w - 4][lane][g * 4] = acc0[g];
      }
      __syncthreads();
      if (w < 4) {
        #pragma unroll
        for (int g = 0; g < 4; ++g) acc0[g] += *(const f32x4*)&red[w][lane][g * 4];
      }
      __syncthreads();
      if (w >= 4) {
        #pragma unroll
        for (int g = 0; g < 4; ++g) *(f32x4*)&red[w - 4][lane][g * 4] = acc1[g];
      }
      __syncthreads();
      if (w < 4) {
        #pragma unroll
        for (int g = 0; g < 4; ++g) acc1[g] += *(const f32x4*)&red[w][lane][g * 4];

        if (role == 1) {
          // coalesced full-K partials: u64 agent stores (compiler-tracked)
          float* pw = pabuf + (size_t)(t & 1) * 524288 + (size_t)(cslice * 4 + w) * 2048;
          #pragma unroll
          for (int g = 0; g < 4; ++g) {
            st_agent((u64*)pw + g * 128 + lane * 2,           pack2f(acc0[g][0], acc0[g][1]));
            st_agent((u64*)pw + g * 128 + lane * 2 + 1,       pack2f(acc0[g][2], acc0[g][3]));
            st_agent((u64*)pw + (4 + g) * 128 + lane * 2,     pack2f(acc1[g][0], acc1[g][1]));
            st_agent((u64*)pw + (4 + g) * 128 + lane * 2 + 1, pack2f(acc1[g][2], acc1[g][3]));
          }
        } else {
          #pragma unroll
          for (int mt = 0; mt < 2; ++mt) {
            #pragma unroll
            for (int r = 0; r < 4; ++r) {
              float xi, xf, xg, xo;
              f32x4* a = mt ? acc1 : acc0;
              if (role == 0) {
                xi = a[0][r] + gx[mt][0][r];
                xf = a[1][r] + gx[mt][1][r];
                xg = a[2][r] + gx[mt][2][r];
                xo = a[3][r] + gx[mt][3][r];
              } else {
                const int h2 = r >> 1, lo = r & 1;
                auto up = [&](int j) {
                  u64 v = pa64[j * 2 + h2];
                  return __uint_as_float(lo ? (unsigned)(v >> 32) : (unsigned)v);
                };
                xi = a[0][r] + up(mt * 4 + 0) + b1[0];
                xf = a[1][r] + up(mt * 4 + 1) + b1[1];
                xg = a[2][r] + up(mt * 4 + 2) + b1[2];
                xo = a[3][r] + up(mt * 4 + 3) + b1[3];
              }
              float i_ = sigm_(xi), f_ = sigm_(xf), g_ = tanh_(xg), o_ = sigm_(xo);
              float cn = f_ * c_st[mt][r] + i_ * g_;
              c_st[mt][r] = cn;
              float h = o_ * tanh_(cn);
              stage[w * 32 + mt * 16 + q * 4 + r][l15] = h;   // f32 h to LDS stage
            }
          }
        }
      }

      // ---- coalesced h / out stores (role0 & role2; all 512 threads) ----
      if (role != 1) {
        __syncthreads();                       // stage[] ready
        const int row = tid >> 2, qt = tid & 3;
        f32x4 v = *(const f32x4*)&stage[row][qt * 4];
        u64 pk = pack4bf(v);
        if (role == 0) {
          st_agent((u64*)(h0ring + (size_t)(t & 1) * HSLOT + ((size_t)row << 10) + cb) + qt, pk);
        } else {
          st_agent((u64*)(h1ring + (size_t)(t & 1) * HSLOT + ((size_t)row << 10) + cb) + qt, pk);
          // out has NO cross-block reader: plain cached store, kernel-end writeback
          *(f32x4*)(out + (size_t)row * ((size_t)T_SEQ * 1024) + (size_t)t * 1024 + cb + qt * 4) = v;
        }
      }
    }

    // ---- grid barrier: parallel flag stores + master scan + epoch bcast ----
    __syncthreads();                 // per-wave vmcnt drain (atomic stores tracked)
    const int need = p + 1;
    if (tid == 0) st_agent(flags + bid, need);
    if (bid == 0 && w == 0) {        // master wave scans 192 flags, 3 per lane
      bool ok;
      do {
        int f0 = ld_agent(flags + lane);
        int f1 = ld_agent(flags + 64 + lane);
        int f2 = ld_agent(flags + 128 + lane);
        ok = __all(min(f0, min(f1, f2)) >= need);
        if (!ok) __builtin_amdgcn_s_sleep(1);
      } while (!ok);
      if (lane == 0) st_agent(epoch, need);
    }
    if (tid == 0) {
      while (ld_agent(epoch) < need) __builtin_amdgcn_s_sleep(1);
      __builtin_amdgcn_fence(__ATOMIC_ACQUIRE, "agent");   // buffer_inv, no wbl2
    }
    __syncthreads();
  }
}

// ---------- launch ----------
extern "C" void kernel_launch(void* const* d_in, const int* in_sizes, int n_in,
                              void* d_out, int out_size, void* d_ws, size_t ws_size,
                              hipStream_t stream) {
  (void)in_sizes; (void)n_in; (void)out_size; (void)ws_size;
  const float* x    = (const float*)d_in[0];
  const float* fc_w = (const float*)d_in[1];
  const float* fc_b = (const float*)d_in[2];
  const float* Wih0 = (const float*)d_in[3];
  const float* Whh0 = (const float*)d_in[4];
  const float* bih0 = (const float*)d_in[5];
  const float* bhh0 = (const float*)d_in[6];
  const float* Wih1 = (const float*)d_in[7];
  const float* Whh1 = (const float*)d_in[8];
  const float* bih1 = (const float*)d_in[9];
  const float* bhh1 = (const float*)d_in[10];
  float* out = (float*)d_out;

  char* ws = (char*)d_ws;
  size_t off = 0;
  auto alloc = [&](size_t bytes) -> void* {
    void* p = ws + off;
    off += (bytes + 255) & ~(size_t)255;
    return p;
  };
  float* z      = (float*)alloc((size_t)128 * 1024 * 4);
  float* gx0    = (float*)alloc((size_t)128 * 4096 * 4);
  u16*   h0ring = (u16*)alloc((size_t)2 * 128 * 1024 * 2);
  u16*   h1ring = (u16*)alloc((size_t)2 * 128 * 1024 * 2);
  float* pabuf  = (float*)alloc((size_t)2 * 524288 * 4);
  int*   flags  = (int*)alloc(256 * 4);
  int*   epoch  = (int*)alloc(256);

  hipMemsetAsync(h0ring, 0, (size_t)2 * 128 * 1024 * 2, stream);
  hipMemsetAsync(h1ring, 0, (size_t)2 * 128 * 1024 * 2, stream);
  hipMemsetAsync(flags, 0, 256 * 4, stream);
  hipMemsetAsync(epoch, 0, 256, stream);

  fc_kernel<<<512, 256, 0, stream>>>(x, fc_w, fc_b, z);
  gx0_kernel<<<2048, 256, 0, stream>>>(z, Wih0, bih0, bhh0, gx0);

  lstm_persist<<<NBLK, 512, 0, stream>>>(Whh0, Wih1, Whh1, gx0, bih1, bhh1,
                                         h0ring, h1ring, pabuf, out, flags, epoch);
}

// Round 6
// 7431.966 us; speedup vs baseline: 2.4540x; 1.0436x over previous
//
#include <hip/hip_runtime.h>

typedef __attribute__((ext_vector_type(8))) short bf16x8;   // 8 bf16 (4 VGPRs)
typedef __attribute__((ext_vector_type(4))) float f32x4;
typedef unsigned short u16;
typedef unsigned long long u64;

#define T_SEQ 512
#define NBLK  192
#define FPAD  16        // ints per flag slot = one 64B line per block

__device__ __forceinline__ u16 f2bf(float f) {
  unsigned int u = __float_as_uint(f);
  u += 0x7fffu + ((u >> 16) & 1u);           // RNE
  return (u16)(u >> 16);
}
__device__ __forceinline__ float sigm_(float x) { return 1.f / (1.f + __expf(-x)); }
__device__ __forceinline__ float tanh_(float x) { return 1.f - 2.f / (__expf(2.f * x) + 1.f); }

// agent-scope (device-coherent) access. COMPILER-VISIBLE (tracked by vmcnt
// insertion, drained before every s_barrier). No wbl2 needed.
template <typename T>
__device__ __forceinline__ void st_agent(T* p, T v) {
  __hip_atomic_store(p, v, __ATOMIC_RELAXED, __HIP_MEMORY_SCOPE_AGENT);
}
template <typename T>
__device__ __forceinline__ T ld_agent(const T* p) {
  return __hip_atomic_load(p, __ATOMIC_RELAXED, __HIP_MEMORY_SCOPE_AGENT);
}
__device__ __forceinline__ u64 pack2f(float a, float b) {
  return (u64)__float_as_uint(a) | ((u64)__float_as_uint(b) << 32);
}
__device__ __forceinline__ u64 pack4bf(f32x4 v) {
  return (u64)f2bf(v[0]) | ((u64)f2bf(v[1]) << 16) |
         ((u64)f2bf(v[2]) << 32) | ((u64)f2bf(v[3]) << 48);
}

// ---------- prologue kernels ----------
__global__ void fc_kernel(const float* __restrict__ x, const float* __restrict__ w,
                          const float* __restrict__ bias, float* __restrict__ z) {
  int idx = blockIdx.x * 256 + threadIdx.x;    // 131072 = 128*1024
  int b = idx >> 10, i = idx & 1023;
  const float* xr = x + b * 256;
  const float* wr = w + i * 256;
  float acc = bias[i];
  #pragma unroll 4
  for (int o = 0; o < 256; ++o) acc += xr[o] * wr[o];
  z[idx] = acc;
}

__global__ void gx0_kernel(const float* __restrict__ z, const float* __restrict__ Wih0,
                           const float* __restrict__ bih, const float* __restrict__ bhh,
                           float* __restrict__ gx0) {
  int idx = blockIdx.x * 256 + threadIdx.x;    // 524288 = 128*4096
  int b = idx >> 12, j = idx & 4095;
  const float* zr = z + b * 1024;
  const float* wr = Wih0 + (size_t)j * 1024;
  float acc = bih[j] + bhh[j];
  #pragma unroll 4
  for (int k = 0; k < 1024; ++k) acc += zr[k] * wr[k];
  gx0[idx] = acc;
}

// ---------- persistent fused 2-layer LSTM ----------
// 192 blocks x 512 threads, 1 block/CU. Roles:
//   role0: layer0 (W=Whh0 slice, t=p), role1: layer1 input-side -> pabuf (t=p-1),
//   role2: layer1 recur-side + pointwise + out (t=p-2).
// vs R5 (ONLY change): contention-free barrier. flags padded to one 64B line
// per block; epoch is per-block private lines filled by a master-wave
// broadcast (3 stores/lane to 192 distinct lines). No same-line multi-agent
// traffic anywhere in the barrier.
__global__ __launch_bounds__(512, 2)
void lstm_persist(const float* __restrict__ Whh0, const float* __restrict__ Wih1,
                  const float* __restrict__ Whh1, const float* __restrict__ gx0,
                  const float* __restrict__ bih1, const float* __restrict__ bhh1,
                  u16* __restrict__ h0ring, u16* __restrict__ h1ring,
                  float* __restrict__ pabuf, float* __restrict__ out,
                  int* __restrict__ flags, int* __restrict__ epoch) {
  __shared__ __align__(16) u16 wlds[4][2048][8];       // 128 KiB (frag-major W)
  __shared__ __align__(16) float red[4][64][16];       // 16 KiB (K-half reduce)
  __shared__ __align__(16) float stage[128][16];       // 8 KiB (h staging)

  const int bid = blockIdx.x;
  const int role = bid >> 6;
  const int cslice = bid & 63;
  const int cb = cslice * 16;        // h-col base
  const int tid = threadIdx.x;
  const int w = tid >> 6;            // wave 0..7
  const int lane = tid & 63;
  const int l15 = lane & 15;
  const int q = lane >> 4;
  const int Mg = w & 3;              // M-group: batches Mg*32..+32
  const int kh = w >> 2;             // K-half

  // ---- stage W slice fp32 -> bf16 -> LDS (once) ----
  {
    const float* Wsrc = (role == 0) ? Whh0 : (role == 1) ? Wih1 : Whh1;
    const int r = tid >> 3;          // 0..63: row within slice
    const int g = r >> 4, n = r & 15;
    const int k0 = (tid & 7) * 128;
    const float* src = Wsrc + (((size_t)(g * 1024 + cb + n)) << 10) + k0;
    for (int k = 0; k < 128; k += 4) {
      float4 v = *(const float4*)(src + k);
      ushort4 o;
      o.x = f2bf(v.x); o.y = f2bf(v.y); o.z = f2bf(v.z); o.w = f2bf(v.w);
      const int kk = k0 + k;
      *(ushort4*)&wlds[g][((kk >> 3) << 4) + n][kk & 7] = o;
    }
  }

  // ---- per-thread persistent state ----
  float c_st[2][4];
  #pragma unroll
  for (int mt = 0; mt < 2; ++mt)
    #pragma unroll
    for (int r = 0; r < 4; ++r) c_st[mt][r] = 0.f;

  float gx[2][4][4];                 // role0: gx0 base slice
  float b1[4];                       // role2: bias
  if (role == 0 && w < 4) {
    #pragma unroll
    for (int mt = 0; mt < 2; ++mt)
      #pragma unroll
      for (int g = 0; g < 4; ++g)
        #pragma unroll
        for (int r = 0; r < 4; ++r)
          gx[mt][g][r] = gx0[(size_t)(w * 32 + mt * 16 + q * 4 + r) * 4096 + g * 1024 + cb + l15];
  }
  if (role == 2 && w < 4) {
    #pragma unroll
    for (int g = 0; g < 4; ++g)
      b1[g] = bih1[g * 1024 + cb + l15] + bhh1[g * 1024 + cb + l15];
  }
  __syncthreads();

  const size_t HSLOT = (size_t)128 * 1024;   // elems per h ring slot

  for (int p = 0; p < T_SEQ + 2; ++p) {
    const int t = p - role;
    if (t >= 0 && t < T_SEQ) {
      const u16* A;
      if (role == 1)      A = h0ring + (size_t)(t & 1) * HSLOT;
      else if (role == 0) A = h0ring + (size_t)((t + 1) & 1) * HSLOT;
      else                A = h1ring + (size_t)((t + 1) & 1) * HSLOT;

      const int kbase = kh * 512;
      const u16* Ap = A + (((size_t)(Mg * 32 + l15)) << 10) + kbase + q * 8;
      const int cellbase = ((kbase >> 3) + q) * 16 + l15;   // + kk*64

      f32x4 acc0[4] = {{0.f,0.f,0.f,0.f},{0.f,0.f,0.f,0.f},{0.f,0.f,0.f,0.f},{0.f,0.f,0.f,0.f}};
      f32x4 acc1[4] = {{0.f,0.f,0.f,0.f},{0.f,0.f,0.f,0.f},{0.f,0.f,0.f,0.f},{0.f,0.f,0.f,0.f}};

      #pragma unroll
      for (int kk = 0; kk < 16; ++kk) {
        bf16x8 a0 = *(const bf16x8*)(Ap + kk * 32);
        bf16x8 a1 = *(const bf16x8*)(Ap + (16 << 10) + kk * 32);
        #pragma unroll
        for (int g = 0; g < 4; ++g) {
          bf16x8 b = *(const bf16x8*)&wlds[g][cellbase + kk * 64][0];
          acc0[g] = __builtin_amdgcn_mfma_f32_16x16x32_bf16(a0, b, acc0[g], 0, 0, 0);
          acc1[g] = __builtin_amdgcn_mfma_f32_16x16x32_bf16(a1, b, acc1[g], 0, 0, 0);
        }
      }

      // role2: issue pabuf loads early (u64 atomics; compiler inserts the wait
      // before first use, the LDS reduction hides the latency)
      u64 pa64[16];
      const float* pr = pabuf + (size_t)(t & 1) * 524288 + (size_t)(cslice * 4 + w) * 2048;
      if (role == 2 && w < 4) {
        #pragma unroll
        for (int j = 0; j < 8; ++j) {
          pa64[j * 2]     = ld_agent((const u64*)pr + j * 128 + lane * 2);
          pa64[j * 2 + 1] = ld_agent((const u64*)pr + j * 128 + lane * 2 + 1);
        }
      }

      // ---- K-half reduction via LDS ----
      if (w >= 4) {
        #pragma unroll
        for (int g = 0; g < 4; ++g) *(f32x4*)&red[w - 4][lane][g * 4] = acc0[g];
      }
      __syncthreads();
      if (w < 4) {
        #pragma unroll
        for (int g = 0; g < 4; ++g) acc0[g] += *(const f32x4*)&red[w][lane][g * 4];
      }
      __syncthreads();
      if (w >= 4) {
        #pragma unroll
        for (int g = 0; g < 4; ++g) *(f32x4*)&red[w - 4][lane][g * 4] = acc1[g];
      }
      __syncthreads();
      if (w < 4) {
        #pragma unroll
        for (int g = 0; g < 4; ++g) acc1[g] += *(const f32x4*)&red[w][lane][g * 4];

        if (role == 1) {
          // coalesced full-K partials: u64 agent stores (compiler-tracked)
          float* pw = pabuf + (size_t)(t & 1) * 524288 + (size_t)(cslice * 4 + w) * 2048;
          #pragma unroll
          for (int g = 0; g < 4; ++g) {
            st_agent((u64*)pw + g * 128 + lane * 2,           pack2f(acc0[g][0], acc0[g][1]));
            st_agent((u64*)pw + g * 128 + lane * 2 + 1,       pack2f(acc0[g][2], acc0[g][3]));
            st_agent((u64*)pw + (4 + g) * 128 + lane * 2,     pack2f(acc1[g][0], acc1[g][1]));
            st_agent((u64*)pw + (4 + g) * 128 + lane * 2 + 1, pack2f(acc1[g][2], acc1[g][3]));
          }
        } else {
          #pragma unroll
          for (int mt = 0; mt < 2; ++mt) {
            #pragma unroll
            for (int r = 0; r < 4; ++r) {
              float xi, xf, xg, xo;
              f32x4* a = mt ? acc1 : acc0;
              if (role == 0) {
                xi = a[0][r] + gx[mt][0][r];
                xf = a[1][r] + gx[mt][1][r];
                xg = a[2][r] + gx[mt][2][r];
                xo = a[3][r] + gx[mt][3][r];
              } else {
                const int h2 = r >> 1, lo = r & 1;
                auto up = [&](int j) {
                  u64 v = pa64[j * 2 + h2];
                  return __uint_as_float(lo ? (unsigned)(v >> 32) : (unsigned)v);
                };
                xi = a[0][r] + up(mt * 4 + 0) + b1[0];
                xf = a[1][r] + up(mt * 4 + 1) + b1[1];
                xg = a[2][r] + up(mt * 4 + 2) + b1[2];
                xo = a[3][r] + up(mt * 4 + 3) + b1[3];
              }
              float i_ = sigm_(xi), f_ = sigm_(xf), g_ = tanh_(xg), o_ = sigm_(xo);
              float cn = f_ * c_st[mt][r] + i_ * g_;
              c_st[mt][r] = cn;
              float h = o_ * tanh_(cn);
              stage[w * 32 + mt * 16 + q * 4 + r][l15] = h;   // f32 h to LDS stage
            }
          }
        }
      }

      // ---- coalesced h / out stores (role0 & role2; all 512 threads) ----
      if (role != 1) {
        __syncthreads();                       // stage[] ready
        const int row = tid >> 2, qt = tid & 3;
        f32x4 v = *(const f32x4*)&stage[row][qt * 4];
        u64 pk = pack4bf(v);
        if (role == 0) {
          st_agent((u64*)(h0ring + (size_t)(t & 1) * HSLOT + ((size_t)row << 10) + cb) + qt, pk);
        } else {
          st_agent((u64*)(h1ring + (size_t)(t & 1) * HSLOT + ((size_t)row << 10) + cb) + qt, pk);
          // out has NO cross-block reader: plain cached store, kernel-end writeback
          *(f32x4*)(out + (size_t)row * ((size_t)T_SEQ * 1024) + (size_t)t * 1024 + cb + qt * 4) = v;
        }
      }
    }

    // ---- contention-free grid barrier ----
    // arrive: one store per block to its PRIVATE 64B line.
    // master wave: scan 192 distinct lines; broadcast epoch to 192 PRIVATE lines.
    // depart: each block polls only its own epoch line. No same-line sharing.
    __syncthreads();                 // per-wave vmcnt drain (atomic stores tracked)
    const int need = p + 1;
    if (tid == 0) st_agent(flags + bid * FPAD, need);
    if (bid == 0 && w == 0) {        // master wave: 3 lines per lane
      bool ok;
      do {
        int f0 = ld_agent(flags + lane * FPAD);
        int f1 = ld_agent(flags + (64 + lane) * FPAD);
        int f2 = ld_agent(flags + (128 + lane) * FPAD);
        ok = __all(min(f0, min(f1, f2)) >= need);
        if (!ok) __builtin_amdgcn_s_sleep(1);
      } while (!ok);
      st_agent(epoch + lane * FPAD, need);          // broadcast: 192 distinct lines
      st_agent(epoch + (64 + lane) * FPAD, need);
      st_agent(epoch + (128 + lane) * FPAD, need);
    }
    if (tid == 0) {
      while (ld_agent(epoch + bid * FPAD) < need) __builtin_amdgcn_s_sleep(1);
      __builtin_amdgcn_fence(__ATOMIC_ACQUIRE, "agent");   // buffer_inv, no wbl2
    }
    __syncthreads();
  }
}

// ---------- launch ----------
extern "C" void kernel_launch(void* const* d_in, const int* in_sizes, int n_in,
                              void* d_out, int out_size, void* d_ws, size_t ws_size,
                              hipStream_t stream) {
  (void)in_sizes; (void)n_in; (void)out_size; (void)ws_size;
  const float* x    = (const float*)d_in[0];
  const float* fc_w = (const float*)d_in[1];
  const float* fc_b = (const float*)d_in[2];
  const float* Wih0 = (const float*)d_in[3];
  const float* Whh0 = (const float*)d_in[4];
  const float* bih0 = (const float*)d_in[5];
  const float* bhh0 = (const float*)d_in[6];
  const float* Wih1 = (const float*)d_in[7];
  const float* Whh1 = (const float*)d_in[8];
  const float* bih1 = (const float*)d_in[9];
  const float* bhh1 = (const float*)d_in[10];
  float* out = (float*)d_out;

  char* ws = (char*)d_ws;
  size_t off = 0;
  auto alloc = [&](size_t bytes) -> void* {
    void* p = ws + off;
    off += (bytes + 255) & ~(size_t)255;
    return p;
  };
  float* z      = (float*)alloc((size_t)128 * 1024 * 4);
  float* gx0    = (float*)alloc((size_t)128 * 4096 * 4);
  u16*   h0ring = (u16*)alloc((size_t)2 * 128 * 1024 * 2);
  u16*   h1ring = (u16*)alloc((size_t)2 * 128 * 1024 * 2);
  float* pabuf  = (float*)alloc((size_t)2 * 524288 * 4);
  int*   flags  = (int*)alloc(NBLK * FPAD * 4);
  int*   epoch  = (int*)alloc(NBLK * FPAD * 4);

  hipMemsetAsync(h0ring, 0, (size_t)2 * 128 * 1024 * 2, stream);
  hipMemsetAsync(h1ring, 0, (size_t)2 * 128 * 1024 * 2, stream);
  hipMemsetAsync(flags, 0, NBLK * FPAD * 4, stream);
  hipMemsetAsync(epoch, 0, NBLK * FPAD * 4, stream);

  fc_kernel<<<512, 256, 0, stream>>>(x, fc_w, fc_b, z);
  gx0_kernel<<<2048, 256, 0, stream>>>(z, Wih0, bih0, bhh0, gx0);

  lstm_persist<<<NBLK, 512, 0, stream>>>(Whh0, Wih1, Whh1, gx0, bih1, bhh1,
                                         h0ring, h1ring, pabuf, out, flags, epoch);
}